// Round 7
// baseline (1336.058 us; speedup 1.0000x reference)
//
#include <hip/hip_runtime.h>
#include <math.h>

// PLRNN forward via MFMA matvec. 256 batches x 1024 steps, 1 WG (512 thr,
// 8 waves) per batch, 1 per CU. Weights resident as f16 MFMA fragments.
// Per step (2 barriers):
//   p1 (M-split): wave w -> pre rows [64w,64w+64): 4x4 MFMA 16x16x32, C-in=h2.
//   bounce (wave-local): relu+f16, masked write r[64w..64w+64) -> rt.
//   p2 (K-split): wave w -> partials u[0..127] over k in [64w,64w+64): 8x2 MFMA
//       reading ONLY its own bounce rows (no barrier); + tail MFMA for mt==w
//       covering k=512..543 = [C | h1 | 0] x [s~ | 1 | 0].
//   part write (masked, conflict-free), B1.
//   reduce: 2 b128 reads of part (stride 136 -> <=2-way) + xor1/xor2 DPP adds.
//   update (distributed, rows 16w+4zb..+4): znew = A*zf + u; TF via Xc; 4
//       writer lanes publish zf_h (f16) + outc; wave 7 stages s~(t+1). B2.
// X/S/out staged in LDS per 128-step chunk -> no global ops in steady state.

#define NB 256
#define T  1024
#define DX 64
#define DZ 128
#define DH 512
#define DS 16
#define CHUNK 128
#define PSTR 136            // part row stride (floats): 136 % 32 == 8 -> 2-way max

typedef _Float16 half8 __attribute__((ext_vector_type(8)));
typedef _Float16 v4h   __attribute__((ext_vector_type(4)));
typedef float    f32x4 __attribute__((ext_vector_type(4)));

__device__ __forceinline__ half8 cvt8(const float* __restrict__ src) {
  const float4 a = *reinterpret_cast<const float4*>(src);
  const float4 c = *reinterpret_cast<const float4*>(src + 4);
  half8 h;
  h[0] = (_Float16)a.x; h[1] = (_Float16)a.y; h[2] = (_Float16)a.z; h[3] = (_Float16)a.w;
  h[4] = (_Float16)c.x; h[5] = (_Float16)c.y; h[6] = (_Float16)c.z; h[7] = (_Float16)c.w;
  return h;
}

template <int CTRL>
__device__ __forceinline__ f32x4 dpp_xor_add(f32x4 v) {   // v += v[lane^d] (in-quad)
  f32x4 r;
  #pragma unroll
  for (int j = 0; j < 4; ++j) {
    const int t = __builtin_amdgcn_update_dpp(0, __float_as_int(v[j]), CTRL, 0xF, 0xF, true);
    r[j] = v[j] + __int_as_float(t);
  }
  return r;
}

__global__ __launch_bounds__(512, 2) void plrnn_kernel(
    const float* __restrict__ X, const float* __restrict__ S,
    const float* __restrict__ A, const float* __restrict__ W1,
    const float* __restrict__ W2, const float* __restrict__ h1,
    const float* __restrict__ h2, const float* __restrict__ C,
    float* __restrict__ out)
{
  __shared__ __align__(16) _Float16 zf_h[DZ];          // 256 B
  __shared__ __align__(16) _Float16 rt[544];           // r(512) + s~(16) + [1,0..](16)
  __shared__ __align__(16) float    part[8][PSTR];     // 4.25 KiB, stride-tuned
  __shared__ __align__(16) float    Xc[CHUNK][DX];     // 32 KiB: X[t+1 .. t+128]
  __shared__ __align__(16) float    Sc[CHUNK][DS];     // 8 KiB:  S[t .. t+127]
  __shared__ __align__(16) float    outc[CHUNK][DX];   // 32 KiB

  const int b   = blockIdx.x;
  const int tid = threadIdx.x;
  const int w   = tid >> 6;            // wave 0..7
  const int l   = tid & 63;
  const int g   = l >> 4;              // 16-lane group (B k-slice / D row-block)
  const int r15 = l & 15;              // A row-in-tile / D col
  const int zb  = (l >> 2) & 3;        // update row-block (rows 16w+4zb..+4)
  const int a4  = l & 3;               // partial index for reduce

  // ---- one-time: stage chunk 0 (X rows 1..128 clamped, S rows 0..127) ----
  {
    #pragma unroll
    for (int k = 0; k < 4; ++k) {
      const int flat = k * 2048 + tid * 4;
      int srow = 1 + (flat >> 6);
      if (srow > T - 1) srow = T - 1;
      const float4 v = *reinterpret_cast<const float4*>(X + ((size_t)b * T + srow) * DX + (flat & 63));
      *reinterpret_cast<float4*>(&((float*)Xc)[flat]) = v;
    }
    const int flat = tid * 4;
    const float4 v = *reinterpret_cast<const float4*>(S + ((size_t)b * T) * DS + flat);
    *reinterpret_cast<float4*>(&((float*)Sc)[flat]) = v;
  }

  // ---- one-time: rt tail constants + s~(0) from global ----
  if (tid < 16) {
    rt[528 + tid] = (tid == 0) ? (_Float16)1.0f : (_Float16)0.0f;
    rt[512 + tid] = (_Float16)S[((size_t)b * T) * DS + tid];
  }

  // ---- one-time: W2 A-fragments (wave w: rows 64w+16mt+r15, k=32kt+8g+e) ----
  half8 w2f[4][4];
  #pragma unroll
  for (int mt = 0; mt < 4; ++mt)
    #pragma unroll
    for (int kt = 0; kt < 4; ++kt)
      w2f[mt][kt] = cvt8(W2 + ((size_t)b * DH + 64 * w + 16 * mt + r15) * DZ + 32 * kt + 8 * g);

  // ---- one-time: W1 A-fragments (rows 16mt+r15, k=64w+32kt+8g+e) ----
  half8 w1f[8][2];
  #pragma unroll
  for (int mt = 0; mt < 8; ++mt)
    #pragma unroll
    for (int kt = 0; kt < 2; ++kt)
      w1f[mt][kt] = cvt8(W1 + ((size_t)b * DZ + 16 * mt + r15) * DH + 64 * w + 32 * kt + 8 * g);

  // ---- one-time: per-wave tail fragment (rows 16w+r15, k-lane 8g+e) ----
  half8 w1ft;
  #pragma unroll
  for (int e = 0; e < 8; ++e) w1ft[e] = (_Float16)0.0f;
  {
    const int row = 16 * w + r15;
    if (g == 0)      w1ft = cvt8(C + ((size_t)b * DZ + row) * DS + 0);
    else if (g == 1) w1ft = cvt8(C + ((size_t)b * DZ + row) * DS + 8);
    else if (g == 2) w1ft[0] = (_Float16)h1[(size_t)b * DZ + row];
  }

  // ---- one-time: h2 as acc-init (D rows 4g+j of each mt) ----
  f32x4 h2v[4];
  #pragma unroll
  for (int mt = 0; mt < 4; ++mt)
    h2v[mt] = *reinterpret_cast<const f32x4*>(h2 + (size_t)b * DH + 64 * w + 16 * mt + 4 * g);

  // ---- one-time: update constants (rows 16w+4zb+j; lanes dup x4 over l>>4) ----
  const f32x4 Areg = *reinterpret_cast<const f32x4*>(A + (size_t)b * DZ + 16 * w + 4 * zb);
  f32x4 zfcur = {0.f, 0.f, 0.f, 0.f};
  if (w < 4) {
    const f32x4 x0 = *reinterpret_cast<const f32x4*>(X + ((size_t)b * T) * DX + 16 * w + 4 * zb);
    #pragma unroll
    for (int j = 0; j < 4; ++j) zfcur[j] = (x0[j] != x0[j]) ? 0.f : x0[j];  // zf(0)
  }
  if (l < 16 && a4 == 0) {             // writer lanes l in {0,4,8,12}: one per zb
    v4h zp;
    #pragma unroll
    for (int j = 0; j < 4; ++j) zp[j] = (_Float16)zfcur[j];
    *reinterpret_cast<v4h*>(&zf_h[16 * w + 4 * zb]) = zp;
  }
  __syncthreads();

  const f32x4 zero4 = {0.f, 0.f, 0.f, 0.f};

  for (int t = 0; t < T; ++t) {
    // ---- chunk boundary: flush out-chunk, stage next X/S chunk + s~ ----
    if ((t & (CHUNK - 1)) == 0 && t) {
      const int c0 = t - CHUNK;
      #pragma unroll
      for (int k = 0; k < 4; ++k) {
        const int flat = k * 2048 + tid * 4;
        const float4 v = *reinterpret_cast<const float4*>(&((float*)outc)[flat]);
        *reinterpret_cast<float4*>(out + ((size_t)b * T + c0) * DX + flat) = v;
      }
      #pragma unroll
      for (int k = 0; k < 4; ++k) {
        const int flat = k * 2048 + tid * 4;
        int srow = t + 1 + (flat >> 6);
        if (srow > T - 1) srow = T - 1;
        const float4 v = *reinterpret_cast<const float4*>(X + ((size_t)b * T + srow) * DX + (flat & 63));
        *reinterpret_cast<float4*>(&((float*)Xc)[flat]) = v;
      }
      {
        const int flat = tid * 4;
        const float4 v = *reinterpret_cast<const float4*>(S + ((size_t)b * T + t) * DS + flat);
        *reinterpret_cast<float4*>(&((float*)Sc)[flat]) = v;
      }
      if (tid < 16) rt[512 + tid] = (_Float16)S[((size_t)b * T + t) * DS + tid];
      __syncthreads();
    }
    const int tc = t & (CHUNK - 1);

    // ---- phase 1: pre = h2 + W2·zf (16 MFMA) ----
    half8 bz[4];
    #pragma unroll
    for (int kt = 0; kt < 4; ++kt)
      bz[kt] = *reinterpret_cast<const half8*>(zf_h + 32 * kt + 8 * g);

    f32x4 acc1[4];
    #pragma unroll
    for (int mt = 0; mt < 4; ++mt)
      acc1[mt] = __builtin_amdgcn_mfma_f32_16x16x32_f16(w2f[mt][0], bz[0], h2v[mt], 0, 0, 0);
    #pragma unroll
    for (int kt = 1; kt < 4; ++kt)
      #pragma unroll
      for (int mt = 0; mt < 4; ++mt)
        acc1[mt] = __builtin_amdgcn_mfma_f32_16x16x32_f16(w2f[mt][kt], bz[kt], acc1[mt], 0, 0, 0);

    // ---- bounce (wave-local, masked): relu+f16 write r[64w..64w+64) ----
    if (r15 == 0) {
      #pragma unroll
      for (int mt = 0; mt < 4; ++mt) {
        v4h p;
        p[0] = (_Float16)fmaxf(acc1[mt][0], 0.f);
        p[1] = (_Float16)fmaxf(acc1[mt][1], 0.f);
        p[2] = (_Float16)fmaxf(acc1[mt][2], 0.f);
        p[3] = (_Float16)fmaxf(acc1[mt][3], 0.f);
        *reinterpret_cast<v4h*>(&rt[64 * w + 16 * mt + 4 * g]) = p;
      }
    }

    // ---- phase 2: partials over k=[64w,64w+64) + per-wave tail (17 MFMA) ----
    const half8 br0 = *reinterpret_cast<const half8*>(rt + 64 * w + 8 * g);
    const half8 br1 = *reinterpret_cast<const half8*>(rt + 64 * w + 32 + 8 * g);
    const half8 brt = *reinterpret_cast<const half8*>(rt + 512 + 8 * g);

    const f32x4 tailv = __builtin_amdgcn_mfma_f32_16x16x32_f16(w1ft, brt, zero4, 0, 0, 0);

    f32x4 acc2[8];
    #pragma unroll
    for (int mt = 0; mt < 8; ++mt)
      acc2[mt] = __builtin_amdgcn_mfma_f32_16x16x32_f16(w1f[mt][0], br0,
                                                        (mt == w) ? tailv : zero4, 0, 0, 0);
    #pragma unroll
    for (int mt = 0; mt < 8; ++mt)
      acc2[mt] = __builtin_amdgcn_mfma_f32_16x16x32_f16(w1f[mt][1], br1, acc2[mt], 0, 0, 0);

    // ---- partial write (masked, conflict-free: 4 lanes x 16B per op) ----
    if (r15 == 0) {
      #pragma unroll
      for (int mt = 0; mt < 8; ++mt)
        *reinterpret_cast<f32x4*>(&part[w][16 * mt + 4 * g]) = acc2[mt];
    }
    __syncthreads();   // B1: partials visible

    // ---- reduce: 2 reads (a4, a4+4) + xor1/xor2 DPP -> u rows 16w+4zb..+4 ----
    const f32x4 u1 = *reinterpret_cast<const f32x4*>(&part[a4][16 * w + 4 * zb]);
    const f32x4 u2 = *reinterpret_cast<const f32x4*>(&part[4 + a4][16 * w + 4 * zb]);
    f32x4 u = u1 + u2;
    u = dpp_xor_add<0xB1>(u);          // quad_perm(1,0,3,2): a4^1
    u = dpp_xor_add<0x4E>(u);          // quad_perm(2,3,0,1): a4^2

    // ---- distributed update: rows 16w+4zb+j ----
    f32x4 zn, zfn;
    #pragma unroll
    for (int j = 0; j < 4; ++j) zn[j] = Areg[j] * zfcur[j] + u[j];
    zfn = zn;
    if (w < 4) {
      const f32x4 xv = *reinterpret_cast<const f32x4*>(&Xc[tc][16 * w + 4 * zb]);
      #pragma unroll
      for (int j = 0; j < 4; ++j)
        zfn[j] = (xv[j] != xv[j]) ? zn[j] : (0.125f * xv[j] + 0.875f * zn[j]);
      if (l < 16 && a4 == 0)
        *reinterpret_cast<f32x4*>(&outc[tc][16 * w + 4 * zb]) = zn;
    }
    zfcur = zfn;
    if (l < 16 && a4 == 0) {
      v4h zp;
      #pragma unroll
      for (int j = 0; j < 4; ++j) zp[j] = (_Float16)zfn[j];
      *reinterpret_cast<v4h*>(&zf_h[16 * w + 4 * zb]) = zp;
    }
    // ---- stage s~(t+1) (wave 7; skipped at chunk boundary) ----
    if (w == 7 && l < 4 && ((t + 1) & (CHUNK - 1)) != 0) {
      const f32x4 sv = *reinterpret_cast<const f32x4*>(&Sc[(t + 1) & (CHUNK - 1)][4 * l]);
      v4h sp;
      #pragma unroll
      for (int j = 0; j < 4; ++j) sp[j] = (_Float16)sv[j];
      *reinterpret_cast<v4h*>(&rt[512 + 4 * l]) = sp;
    }
    __syncthreads();   // B2: zf(t+1) + s~(t+1) visible
  }

  // ---- final flush (last chunk) ----
  {
    const int c0 = T - CHUNK;
    #pragma unroll
    for (int k = 0; k < 4; ++k) {
      const int flat = k * 2048 + tid * 4;
      const float4 v = *reinterpret_cast<const float4*>(&((float*)outc)[flat]);
      *reinterpret_cast<float4*>(out + ((size_t)b * T + c0) * DX + flat) = v;
    }
  }
}

extern "C" void kernel_launch(void* const* d_in, const int* in_sizes, int n_in,
                              void* d_out, int out_size, void* d_ws, size_t ws_size,
                              hipStream_t stream) {
  const float* X  = (const float*)d_in[0];
  const float* S  = (const float*)d_in[1];
  const float* A  = (const float*)d_in[2];
  const float* W1 = (const float*)d_in[3];
  const float* W2 = (const float*)d_in[4];
  const float* h1 = (const float*)d_in[5];
  const float* h2 = (const float*)d_in[6];
  const float* C  = (const float*)d_in[7];
  float* out = (float*)d_out;
  plrnn_kernel<<<dim3(NB), dim3(512), 0, stream>>>(X, S, A, W1, W2, h1, h2, C, out);
}

// Round 8
// 1157.317 us; speedup vs baseline: 1.1544x; 1.1544x over previous
//
#include <hip/hip_runtime.h>
#include <math.h>

// PLRNN forward via MFMA matvec. 256 batches x 1024 steps, 1 WG (512 thr,
// 8 waves) per batch, 1 per CU. Weights resident as f16 MFMA fragments.
// R4 skeleton (M-split p2, no post-p2 exchange, 2 barriers) + chain surgery:
//   - X[t+1] prefetched to regs at step start (off-chain)
//   - s~ in per-wave registers; tail MFMA (C.s~) issued before B0
//   - p2 k-order rotated per wave: own k-slices (kt=2w,2w+1) pre-B0
//   - p2 8-way acc split (depth<=3); p1 4-way (depth 4); h1 in f32 VALU
// Per step: p1 (16 MFMA) -> bounce (wave-local) -> tail+own-k p2 (3 MFMA)
//   -> B0 -> p2 rest (14 MFMA) -> distributed update -> B2.
// X/S/out staged in LDS per 128-step chunk -> no global ops in steady state.

#define NB 256
#define T  1024
#define DX 64
#define DZ 128
#define DH 512
#define DS 16
#define CHUNK 128

typedef _Float16 half8 __attribute__((ext_vector_type(8)));
typedef _Float16 v4h   __attribute__((ext_vector_type(4)));
typedef float    f32x4 __attribute__((ext_vector_type(4)));

__device__ __forceinline__ half8 cvt8(const float* __restrict__ src) {
  const float4 a = *reinterpret_cast<const float4*>(src);
  const float4 c = *reinterpret_cast<const float4*>(src + 4);
  half8 h;
  h[0] = (_Float16)a.x; h[1] = (_Float16)a.y; h[2] = (_Float16)a.z; h[3] = (_Float16)a.w;
  h[4] = (_Float16)c.x; h[5] = (_Float16)c.y; h[6] = (_Float16)c.z; h[7] = (_Float16)c.w;
  return h;
}

__global__ __launch_bounds__(512, 2) void plrnn_kernel(
    const float* __restrict__ X, const float* __restrict__ S,
    const float* __restrict__ A, const float* __restrict__ W1,
    const float* __restrict__ W2, const float* __restrict__ h1,
    const float* __restrict__ h2, const float* __restrict__ C,
    float* __restrict__ out)
{
  __shared__ __align__(16) _Float16 zf_h[DZ];          // 256 B
  __shared__ __align__(16) _Float16 rt[DH];            // 1 KiB: relu(pre) f16
  __shared__ __align__(16) float    Xc[CHUNK][DX];     // 32 KiB: X[t+1 .. t+128]
  __shared__ __align__(16) float    Sc[CHUNK][DS];     // 8 KiB:  S[t .. t+127]
  __shared__ __align__(16) float    outc[CHUNK][DX];   // 32 KiB

  const int b   = blockIdx.x;
  const int tid = threadIdx.x;
  const int w   = tid >> 6;            // wave 0..7
  const int l   = tid & 63;
  const int g   = l >> 4;              // 16-lane group (B k-slice / D row-block)
  const int r15 = l & 15;              // A row-in-tile / D col

  // ---- one-time: stage chunk 0 (X rows 1..128 clamped, S rows 0..127) ----
  {
    #pragma unroll
    for (int k = 0; k < 4; ++k) {
      const int flat = k * 2048 + tid * 4;
      int srow = 1 + (flat >> 6);
      if (srow > T - 1) srow = T - 1;
      const float4 v = *reinterpret_cast<const float4*>(X + ((size_t)b * T + srow) * DX + (flat & 63));
      *reinterpret_cast<float4*>(&((float*)Xc)[flat]) = v;
    }
    const int flat = tid * 4;
    const float4 v = *reinterpret_cast<const float4*>(S + ((size_t)b * T) * DS + flat);
    *reinterpret_cast<float4*>(&((float*)Sc)[flat]) = v;
  }

  // ---- one-time: W2 A-fragments (wave w: rows 64w+16mt+r15, k=32kt+8g+e) ----
  half8 w2f[4][4];
  #pragma unroll
  for (int mt = 0; mt < 4; ++mt)
    #pragma unroll
    for (int kt = 0; kt < 4; ++kt)
      w2f[mt][kt] = cvt8(W2 + ((size_t)b * DH + 64 * w + 16 * mt + r15) * DZ + 32 * kt + 8 * g);

  // ---- one-time: W1 A-fragments, rotated k-order: slot j -> kt=(2w+j)&15 ----
  half8 w1f[16];
  #pragma unroll
  for (int j = 0; j < 16; ++j) {
    const int kt = (2 * w + j) & 15;
    w1f[j] = cvt8(W1 + ((size_t)b * DZ + 16 * w + r15) * DH + 32 * kt + 8 * g);
  }

  // ---- one-time: tail A-fragment = C cols (k=512+8g+e, g<2), else 0 ----
  half8 w1ft;
  #pragma unroll
  for (int e = 0; e < 8; ++e) w1ft[e] = (_Float16)0.0f;
  {
    const int row = 16 * w + r15;
    if (g == 0)      w1ft = cvt8(C + ((size_t)b * DZ + row) * DS + 0);
    else if (g == 1) w1ft = cvt8(C + ((size_t)b * DZ + row) * DS + 8);
  }

  // ---- one-time: h2 as acc-init (D rows 4g+j of each mt) ----
  f32x4 h2v[4];
  #pragma unroll
  for (int mt = 0; mt < 4; ++mt)
    h2v[mt] = *reinterpret_cast<const f32x4*>(h2 + (size_t)b * DH + 64 * w + 16 * mt + 4 * g);

  // ---- one-time: update constants (rows 16w+4g+j on r15==0 lanes) ----
  f32x4 Areg = {0.f, 0.f, 0.f, 0.f}, h1reg = {0.f, 0.f, 0.f, 0.f};
  f32x4 zfcur = {0.f, 0.f, 0.f, 0.f};
  if (r15 == 0) {
    Areg  = *reinterpret_cast<const f32x4*>(A  + (size_t)b * DZ + 16 * w + 4 * g);
    h1reg = *reinterpret_cast<const f32x4*>(h1 + (size_t)b * DZ + 16 * w + 4 * g);
    if (w < 4) {
      const f32x4 x0 = *reinterpret_cast<const f32x4*>(X + ((size_t)b * T) * DX + 16 * w + 4 * g);
      #pragma unroll
      for (int j = 0; j < 4; ++j) zfcur[j] = (x0[j] != x0[j]) ? 0.f : x0[j];  // zf(0)
    }
    v4h zp;
    #pragma unroll
    for (int j = 0; j < 4; ++j) zp[j] = (_Float16)zfcur[j];
    *reinterpret_cast<v4h*>(&zf_h[16 * w + 4 * g]) = zp;
  }
  __syncthreads();

  const f32x4 zero4 = {0.f, 0.f, 0.f, 0.f};

  for (int t = 0; t < T; ++t) {
    // ---- chunk boundary: flush out-chunk, stage next X/S chunk ----
    if ((t & (CHUNK - 1)) == 0 && t) {
      const int c0 = t - CHUNK;
      #pragma unroll
      for (int k = 0; k < 4; ++k) {
        const int flat = k * 2048 + tid * 4;
        const float4 v = *reinterpret_cast<const float4*>(&((float*)outc)[flat]);
        *reinterpret_cast<float4*>(out + ((size_t)b * T + c0) * DX + flat) = v;
      }
      #pragma unroll
      for (int k = 0; k < 4; ++k) {
        const int flat = k * 2048 + tid * 4;
        int srow = t + 1 + (flat >> 6);
        if (srow > T - 1) srow = T - 1;
        const float4 v = *reinterpret_cast<const float4*>(X + ((size_t)b * T + srow) * DX + (flat & 63));
        *reinterpret_cast<float4*>(&((float*)Xc)[flat]) = v;
      }
      {
        const int flat = tid * 4;
        const float4 v = *reinterpret_cast<const float4*>(S + ((size_t)b * T + t) * DS + flat);
        *reinterpret_cast<float4*>(&((float*)Sc)[flat]) = v;
      }
      __syncthreads();
    }
    const int tc = t & (CHUNK - 1);

    // ---- off-chain prefetches: X[t+1] row, s~ into registers ----
    const f32x4 xv  = *reinterpret_cast<const f32x4*>(&Xc[tc][16 * (w & 3) + 4 * g]);
    const f32x4 sa0 = *reinterpret_cast<const f32x4*>(&Sc[tc][8 * (g & 1)]);
    const f32x4 sa1 = *reinterpret_cast<const f32x4*>(&Sc[tc][8 * (g & 1) + 4]);
    half8 brt;
    #pragma unroll
    for (int e = 0; e < 4; ++e) {
      brt[e]     = (g < 2) ? (_Float16)sa0[e] : (_Float16)0.0f;
      brt[e + 4] = (g < 2) ? (_Float16)sa1[e] : (_Float16)0.0f;
    }
    // tail MFMA (C·s~): register-only B, issued before B0, overlaps p1
    const f32x4 tailv = __builtin_amdgcn_mfma_f32_16x16x32_f16(w1ft, brt, zero4, 0, 0, 0);

    // ---- phase 1: pre = h2 + W2·zf (16 MFMA, 4 chains) ----
    half8 bz[4];
    #pragma unroll
    for (int kt = 0; kt < 4; ++kt)
      bz[kt] = *reinterpret_cast<const half8*>(zf_h + 32 * kt + 8 * g);

    f32x4 acc1[4];
    #pragma unroll
    for (int mt = 0; mt < 4; ++mt)
      acc1[mt] = __builtin_amdgcn_mfma_f32_16x16x32_f16(w2f[mt][0], bz[0], h2v[mt], 0, 0, 0);
    #pragma unroll
    for (int kt = 1; kt < 4; ++kt)
      #pragma unroll
      for (int mt = 0; mt < 4; ++mt)
        acc1[mt] = __builtin_amdgcn_mfma_f32_16x16x32_f16(w2f[mt][kt], bz[kt], acc1[mt], 0, 0, 0);

    // ---- bounce (wave-local, masked): relu+f16 write r[64w..64w+64) ----
    if (r15 == 0) {
      #pragma unroll
      for (int mt = 0; mt < 4; ++mt) {
        v4h p;
        p[0] = (_Float16)fmaxf(acc1[mt][0], 0.f);
        p[1] = (_Float16)fmaxf(acc1[mt][1], 0.f);
        p[2] = (_Float16)fmaxf(acc1[mt][2], 0.f);
        p[3] = (_Float16)fmaxf(acc1[mt][3], 0.f);
        *reinterpret_cast<v4h*>(&rt[64 * w + 16 * mt + 4 * g]) = p;
      }
    }

    // ---- phase 2 pre-B0: own k-slices kt=2w,2w+1 (wave-local visibility) ----
    f32x4 acc2[8];
    {
      const half8 br0 = *reinterpret_cast<const half8*>(rt + 64 * w + 8 * g);
      const half8 br1 = *reinterpret_cast<const half8*>(rt + 64 * w + 32 + 8 * g);
      acc2[0] = __builtin_amdgcn_mfma_f32_16x16x32_f16(w1f[0], br0, tailv, 0, 0, 0);
      acc2[1] = __builtin_amdgcn_mfma_f32_16x16x32_f16(w1f[1], br1, zero4, 0, 0, 0);
    }
    __syncthreads();   // B0: all waves' r visible

    // ---- phase 2 post-B0: remaining 14 k-slices (8 chains, depth <=3) ----
    #pragma unroll
    for (int j = 2; j < 8; ++j) {
      const half8 br = *reinterpret_cast<const half8*>(rt + 32 * ((2 * w + j) & 15) + 8 * g);
      acc2[j] = __builtin_amdgcn_mfma_f32_16x16x32_f16(w1f[j], br, zero4, 0, 0, 0);
    }
    #pragma unroll
    for (int j = 8; j < 16; ++j) {
      const half8 br = *reinterpret_cast<const half8*>(rt + 32 * ((2 * w + j) & 15) + 8 * g);
      acc2[j - 8] = __builtin_amdgcn_mfma_f32_16x16x32_f16(w1f[j], br, acc2[j - 8], 0, 0, 0);
    }

    // ---- distributed update on D-lanes (rows 16w+4g..+4) ----
    if (r15 == 0) {
      const f32x4 u = ((acc2[0] + acc2[1]) + (acc2[2] + acc2[3]))
                    + ((acc2[4] + acc2[5]) + (acc2[6] + acc2[7]));
      f32x4 zn, zfn;
      #pragma unroll
      for (int j = 0; j < 4; ++j) zn[j] = Areg[j] * zfcur[j] + u[j] + h1reg[j];
      zfn = zn;
      if (w < 4) {
        #pragma unroll
        for (int j = 0; j < 4; ++j)
          zfn[j] = (xv[j] != xv[j]) ? zn[j] : (0.125f * xv[j] + 0.875f * zn[j]);
      }
      zfcur = zfn;
      v4h zp;
      #pragma unroll
      for (int j = 0; j < 4; ++j) zp[j] = (_Float16)zfn[j];
      *reinterpret_cast<v4h*>(&zf_h[16 * w + 4 * g]) = zp;
      if (w < 4)
        *reinterpret_cast<f32x4*>(&outc[tc][16 * w + 4 * g]) = zn;
    }
    __syncthreads();   // B2: zf(t+1) visible
  }

  // ---- final flush (last chunk) ----
  {
    const int c0 = T - CHUNK;
    #pragma unroll
    for (int k = 0; k < 4; ++k) {
      const int flat = k * 2048 + tid * 4;
      const float4 v = *reinterpret_cast<const float4*>(&((float*)outc)[flat]);
      *reinterpret_cast<float4*>(out + ((size_t)b * T + c0) * DX + flat) = v;
    }
  }
}

extern "C" void kernel_launch(void* const* d_in, const int* in_sizes, int n_in,
                              void* d_out, int out_size, void* d_ws, size_t ws_size,
                              hipStream_t stream) {
  const float* X  = (const float*)d_in[0];
  const float* S  = (const float*)d_in[1];
  const float* A  = (const float*)d_in[2];
  const float* W1 = (const float*)d_in[3];
  const float* W2 = (const float*)d_in[4];
  const float* h1 = (const float*)d_in[5];
  const float* h2 = (const float*)d_in[6];
  const float* C  = (const float*)d_in[7];
  float* out = (float*)d_out;
  plrnn_kernel<<<dim3(NB), dim3(512), 0, stream>>>(X, S, A, W1, W2, h1, h2, C, out);
}